// Round 2
// baseline (1020.477 us; speedup 1.0000x reference)
//
#include <hip/hip_runtime.h>

// Problem constants (reference: B=2048, E=32, N=32, D=64)
#define B_  2048
#define E_  32
#define N_  32
#define D_  64

__device__ __forceinline__ float readlane_f(float x, int l) {
    return __int_as_float(__builtin_amdgcn_readlane(__float_as_int(x), l));
}

// One WAVE per (b,e) pair. 4 waves (4 pairs) per 256-thread block.
// Zero __syncthreads, zero LDS: all cross-lane work via shuffles/readlane.
//
// Per-lane data layout: float4 index f = lane + 64*j (j=0..7) over the
// [N=32, D=64] tile (16 float4 per neighbor row). Then
//   d4 = lane & 15   (which float4 within the row — FIXED per lane)
//   n  = (lane>>4) + 4*j  (neighbor index; q = lane>>4 is the n-residue group)
__global__ __launch_bounds__(256) void kgcn_wave_kernel(
    const float* __restrict__ self_v,   // [B,E,D]
    const float* __restrict__ nv,       // [B,E,N,D]
    const float* __restrict__ rel,      // [B,E,N,D]
    const float* __restrict__ user,     // [B,D]
    const float* __restrict__ W,        // [D,D] row-major
    const float* __restrict__ blin,     // [D]
    float* __restrict__ out)            // [B,E,D]
{
    const int t    = threadIdx.x;
    const int wave = t >> 6;
    const int lane = t & 63;
    const int be   = blockIdx.x * 4 + wave;   // 0 .. B*E-1
    const int b    = be >> 5;                 // E = 32
    const int d4   = lane & 15;

    const float4* rel4 = (const float4*)rel + (size_t)be * 512;
    const float4* nv4  = (const float4*)nv  + (size_t)be * 512;

    // ---- issue ALL global loads up front: 16 x float4 = 256 B/lane in flight
    float4 r[8], v[8];
    #pragma unroll
    for (int j = 0; j < 8; ++j) r[j] = rel4[lane + 64 * j];
    #pragma unroll
    for (int j = 0; j < 8; ++j) v[j] = nv4[lane + 64 * j];
    float4 u4 = ((const float4*)user)[b * 16 + d4];
    float4 sv = ((const float4*)self_v)[(size_t)be * 16 + d4];

    // ---- scores[n] = (user . rel[n]) / 64, n = q + 4j ----
    float s[8];
    #pragma unroll
    for (int j = 0; j < 8; ++j) {
        float p = r[j].x * u4.x + r[j].y * u4.y + r[j].z * u4.z + r[j].w * u4.w;
        p += __shfl_xor(p, 1);
        p += __shfl_xor(p, 2);
        p += __shfl_xor(p, 4);
        p += __shfl_xor(p, 8);          // reduce over the 16 d4-lanes of group q
        s[j] = p * (1.0f / 64.0f);
    }

    // ---- softmax over the 32 scores (spread over 4 q-groups x 8 j) ----
    float m = s[0];
    #pragma unroll
    for (int j = 1; j < 8; ++j) m = fmaxf(m, s[j]);
    m = fmaxf(m, __shfl_xor(m, 16));    // across q bit0
    m = fmaxf(m, __shfl_xor(m, 32));    // across q bit1  -> global max

    float e[8];
    float S = 0.0f;
    #pragma unroll
    for (int j = 0; j < 8; ++j) { e[j] = __expf(s[j] - m); S += e[j]; }
    S += __shfl_xor(S, 16);
    S += __shfl_xor(S, 32);             // global sum of exps
    const float inv = 1.0f / (S * (float)N_);   // fold 1/N mean into attn

    // ---- weighted sum over neighbors: partial over this lane's 8 n's ----
    float4 acc = {0.0f, 0.0f, 0.0f, 0.0f};
    #pragma unroll
    for (int j = 0; j < 8; ++j) {
        const float a = e[j] * inv;
        acc.x += a * v[j].x;
        acc.y += a * v[j].y;
        acc.z += a * v[j].z;
        acc.w += a * v[j].w;
    }
    // reduce over the 4 q-groups (same d4, lanes differ in bits 4,5)
    acc.x += __shfl_xor(acc.x, 16);
    acc.y += __shfl_xor(acc.y, 16);
    acc.z += __shfl_xor(acc.z, 16);
    acc.w += __shfl_xor(acc.w, 16);
    acc.x += __shfl_xor(acc.x, 32);
    acc.y += __shfl_xor(acc.y, 32);
    acc.z += __shfl_xor(acc.z, 32);
    acc.w += __shfl_xor(acc.w, 32);

    // residual add (every lane in a d4-group holds the same value — fine)
    acc.x += sv.x; acc.y += sv.y; acc.z += sv.z; acc.w += sv.w;

    // ---- linear + relu: lane l produces out[d = l] ----
    // pre[k] lives at lane k4=k/4 (its d4 == k4); broadcast via v_readlane
    float o = blin[lane];
    const float4* Wr = (const float4*)W + lane * 16;   // W row d=lane
    #pragma unroll
    for (int k4 = 0; k4 < 16; ++k4) {
        float4 w = Wr[k4];
        const float px = readlane_f(acc.x, k4);
        const float py = readlane_f(acc.y, k4);
        const float pz = readlane_f(acc.z, k4);
        const float pw = readlane_f(acc.w, k4);
        o += w.x * px + w.y * py + w.z * pz + w.w * pw;
    }
    out[(size_t)be * 64 + lane] = fmaxf(o, 0.0f);
}

extern "C" void kernel_launch(void* const* d_in, const int* in_sizes, int n_in,
                              void* d_out, int out_size, void* d_ws, size_t ws_size,
                              hipStream_t stream) {
    const float* self_v = (const float*)d_in[0];   // [B,E,D]
    const float* nv     = (const float*)d_in[1];   // [B,E,N,D]
    const float* rel    = (const float*)d_in[2];   // [B,E,N,D]
    const float* user   = (const float*)d_in[3];   // [B,D]
    // d_in[4] = masks (unused by the module)
    const float* W      = (const float*)d_in[5];   // [D,D]
    const float* blin   = (const float*)d_in[6];   // [D]
    float* out          = (float*)d_out;           // [B,E,D]

    const int blocks = (B_ * E_) / 4;              // 16384 blocks x 4 waves
    kgcn_wave_kernel<<<blocks, 256, 0, stream>>>(self_v, nv, rel, user, W, blin, out);
}